// Round 11
// baseline (115.581 us; speedup 1.0000x reference)
//
#include <hip/hip_runtime.h>

// PairwiseLoss: weighted 2-class cross-entropy + top-1 accuracy over all
// probe×gallery pairs.
//   labels[i,j] = (tp[i]==tg[j]); logits[i,j,:] = cls_encode[i,j,0:2]
//   loss = sum(w*nll)/sum(w),  w = label ? 1 : 1/4095
//   prec = 100 * mean(argmax(logits)==label)
//
// R1: libm softplus, predicated -> VALU-bound, 116 us.
// R2: __expf/__logf branch-free softplus -> 33 us.
// R3 FAILED: fused tail w/ per-block __threadfence -> L2 writeback storm
//     (non-coherent per-XCD L2) -> 250 us. Lesson: never fence per block.
// R4-R8: geometry search -> best = 2 rows/block, 2048 blocks (30.3 us).
// R10: NON-TEMPORAL loads on the once-read 134 MB logit stream -> 27.75 us.
// R11: single-kernel finish WITHOUT fences: per-block integer device atomics
//     (coherent-point RMW, no cache writeback) + s_waitcnt vmcnt(0) + ticket.
//     wnll accumulated in fixed-point 2^44 -> exact, commutative, replay-
//     deterministic. Eliminates the 2nd dispatch + graph-node gap (~3 us).

constexpr int BATCH = 4096;
constexpr int NPART = BATCH / 2;           // 2048 blocks, 2 rows each
constexpr float W_NEG_F = 1.0f / 4095.0f;  // matches fp32 W_NEG in reference
constexpr double FIX = 17592186044416.0;   // 2^44 fixed-point scale

typedef float floatx4 __attribute__((ext_vector_type(4)));

__device__ __forceinline__ void pl_pair(float x, float y, bool lab,
                                        float& sum_all, float& sum_pos,
                                        int& pos, int& cor) {
    const float e = y - x;            // d when lab==0
    // log(1+exp(-|d|)) is label-independent since |d|=|e|
    const float t = __logf(1.f + __expf(-fabsf(e)));
    const float m = lab ? fmaxf(-e, 0.f) : fmaxf(e, 0.f);  // max(d,0)
    const float nll = m + t;
    sum_all += nll;
    sum_pos += lab ? nll : 0.f;
    pos += lab ? 1 : 0;
    cor += ((y > x) == lab) ? 1 : 0;  // argmax with first-index tie-break
}

__device__ __forceinline__ floatx4 ntload4(const float* p) {
    return __builtin_nontemporal_load(reinterpret_cast<const floatx4*>(p));
}

// ---------------- fused kernel: partials + atomic finish --------------------
__global__ __launch_bounds__(256) void pl_fused(
    const float* __restrict__ logits,   // [BATCH*BATCH*2]
    const int* __restrict__ tp,         // [BATCH]
    const int* __restrict__ tg,         // [BATCH]
    unsigned long long* __restrict__ acc, // [3]: wnll_fix, pos, cor (zeroed)
    unsigned int* __restrict__ cnt,     // [1] ticket (zeroed)
    float* __restrict__ out)            // out[0]=loss, out[1]=prec
{
    const int t = threadIdx.x;
    const int row0 = 2 * blockIdx.x;
    const float* rowA = logits + (size_t)row0 * (2 * BATCH);
    const float* rowB = rowA + 2 * BATCH;
    const int2* tg2 = reinterpret_cast<const int2*>(tg);

    // All loads upfront, named registers, no barrier before compute.
    // Gallery int2s cached (reused by all blocks); logits NON-TEMPORAL.
    const int2 g0 = tg2[t];
    const int2 g1 = tg2[t + 256];
    const int2 g2 = tg2[t + 512];
    const int2 g3 = tg2[t + 768];
    const int2 g4 = tg2[t + 1024];
    const int2 g5 = tg2[t + 1280];
    const int2 g6 = tg2[t + 1536];
    const int2 g7 = tg2[t + 1792];
    const floatx4 a0 = ntload4(rowA + 4 * t);
    const floatx4 a1 = ntload4(rowA + 4 * (t + 256));
    const floatx4 a2 = ntload4(rowA + 4 * (t + 512));
    const floatx4 a3 = ntload4(rowA + 4 * (t + 768));
    const floatx4 a4 = ntload4(rowA + 4 * (t + 1024));
    const floatx4 a5 = ntload4(rowA + 4 * (t + 1280));
    const floatx4 a6 = ntload4(rowA + 4 * (t + 1536));
    const floatx4 a7 = ntload4(rowA + 4 * (t + 1792));
    const floatx4 b0 = ntload4(rowB + 4 * t);
    const floatx4 b1 = ntload4(rowB + 4 * (t + 256));
    const floatx4 b2 = ntload4(rowB + 4 * (t + 512));
    const floatx4 b3 = ntload4(rowB + 4 * (t + 768));
    const floatx4 b4 = ntload4(rowB + 4 * (t + 1024));
    const floatx4 b5 = ntload4(rowB + 4 * (t + 1280));
    const floatx4 b6 = ntload4(rowB + 4 * (t + 1536));
    const floatx4 b7 = ntload4(rowB + 4 * (t + 1792));
    const int my0 = tp[row0];      // wave-uniform -> scalar loads
    const int my1 = tp[row0 + 1];

    float sum_all = 0.f;   // nll over all pairs this thread sees (both rows)
    float sum_pos = 0.f;   // nll over positive pairs only
    int pos = 0, cor = 0;

#define PL_CHUNK(Q, G, MY)                                                   \
    pl_pair((Q).x, (Q).y, (MY) == (G).x, sum_all, sum_pos, pos, cor);        \
    pl_pair((Q).z, (Q).w, (MY) == (G).y, sum_all, sum_pos, pos, cor);
    PL_CHUNK(a0, g0, my0) PL_CHUNK(a1, g1, my0) PL_CHUNK(a2, g2, my0)
    PL_CHUNK(a3, g3, my0) PL_CHUNK(a4, g4, my0) PL_CHUNK(a5, g5, my0)
    PL_CHUNK(a6, g6, my0) PL_CHUNK(a7, g7, my0)
    PL_CHUNK(b0, g0, my1) PL_CHUNK(b1, g1, my1) PL_CHUNK(b2, g2, my1)
    PL_CHUNK(b3, g3, my1) PL_CHUNK(b4, g4, my1) PL_CHUNK(b5, g5, my1)
    PL_CHUNK(b6, g6, my1) PL_CHUNK(b7, g7, my1)
#undef PL_CHUNK

    // weighted combination, then wave64 shuffle reduce (double for the sum)
    double dw = (double)W_NEG_F * (double)sum_all +
                (1.0 - (double)W_NEG_F) * (double)sum_pos;
#pragma unroll
    for (int off = 32; off > 0; off >>= 1) {
        dw += __shfl_down(dw, off);
        pos += __shfl_down(pos, off);
        cor += __shfl_down(cor, off);
    }
    __shared__ double s_dw[4];
    __shared__ int s_pos[4], s_cor[4];
    const int wave = t >> 6, lane = t & 63;
    if (lane == 0) { s_dw[wave] = dw; s_pos[wave] = pos; s_cor[wave] = cor; }
    __syncthreads();  // tail only — all loads already consumed

    if (t == 0) {
        const double bdw = s_dw[0] + s_dw[1] + s_dw[2] + s_dw[3];
        const int bpos = s_pos[0] + s_pos[1] + s_pos[2] + s_pos[3];
        const int bcor = s_cor[0] + s_cor[1] + s_cor[2] + s_cor[3];

        // Exact, commutative, replay-deterministic integer accumulation at
        // the coherent point. NO __threadfence (no L2 writeback storm).
        const unsigned long long dq =
            (unsigned long long)llrint(bdw * FIX);   // <= ~10*2^44 per block
        atomicAdd(&acc[0], dq);
        atomicAdd(&acc[1], (unsigned long long)bpos);
        atomicAdd(&acc[2], (unsigned long long)bcor);
        // Ensure this block's data atomics have completed (retired at the
        // coherent point) before the ticket increments.
        asm volatile("s_waitcnt vmcnt(0)" ::: "memory");
        const unsigned prev = atomicAdd(cnt, 1u);
        if (prev == (unsigned)(NPART - 1)) {
            // Last block: all 2048 data-atomic sets are complete. Read via
            // atomic RMW(+0) so reads go to the coherent point (never stale).
            const unsigned long long tq = atomicAdd(&acc[0], 0ull);
            const unsigned long long P = atomicAdd(&acc[1], 0ull);
            const unsigned long long C = atomicAdd(&acc[2], 0ull);
            const double tot = (double)tq * (1.0 / FIX);
            const double NP = (double)BATCH * (double)BATCH;
            const double sum_w =
                (double)P + (NP - (double)P) * (double)W_NEG_F;
            out[0] = (float)(tot / sum_w);
            out[1] = (float)(100.0 * (double)C / NP);
        }
    }
}

extern "C" void kernel_launch(void* const* d_in, const int* in_sizes, int n_in,
                              void* d_out, int out_size, void* d_ws, size_t ws_size,
                              hipStream_t stream) {
    const float* logits = (const float*)d_in[0];  // cls_encode [4096,4096,2] f32
    const int* tp = (const int*)d_in[1];          // tar_probe  [4096] i32
    const int* tg = (const int*)d_in[2];          // tar_gallery[4096] i32
    float* out = (float*)d_out;                   // [loss, prec]

    // workspace: acc[3] (u64) | ticket (u32) — zeroed every call
    unsigned long long* acc = (unsigned long long*)d_ws;
    unsigned int* cnt = (unsigned int*)(acc + 3);

    hipMemsetAsync(d_ws, 0, 32, stream);  // stream-ordered memset node
    pl_fused<<<NPART, 256, 0, stream>>>(logits, tp, tg, acc, cnt, out);
}

// Round 12
// 27.706 us; speedup vs baseline: 4.1718x; 4.1718x over previous
//
#include <hip/hip_runtime.h>

// PairwiseLoss: weighted 2-class cross-entropy + top-1 accuracy over all
// probe×gallery pairs.
//   labels[i,j] = (tp[i]==tg[j]); logits[i,j,:] = cls_encode[i,j,0:2]
//   loss = sum(w*nll)/sum(w),  w = label ? 1 : 1/4095
//   prec = 100 * mean(argmax(logits)==label)
//
// Final structure (R12 == R10, the measured best at 27.75 us):
//   kernel 1: 2048 blocks x 256 thr, 2 rows/block, NT float4 loads on the
//             once-read 134 MB logit stream, cached int2 gallery loads,
//             branch-free __expf/__logf softplus, per-block partials.
//   kernel 2: 1 block, fixed-order deterministic final reduce.
// Journal:
// R1: libm softplus, predicated -> VALU-bound, 116 us.
// R2: __expf/__logf branch-free softplus -> 33 us.
// R3 FAILED: fused tail w/ per-block __threadfence -> L2 writeback storm
//     (non-coherent per-XCD L2) -> 250 us.
// R4: loads hoisted above LDS barrier -> 31.7 us (barrier drains vmcnt).
// R5: no barrier, all loads upfront -> 31.6 us (neutral: TLP suffices).
// R6: 2 rows/block, 2048 blocks -> 30.3 us (per-block overhead was slack).
// R7: 8 rows/block, 512 blocks -> 31.1 us (grid-starved occupancy).
// R8: 4 rows/block, 1024 blocks -> 30.5 us (overhead lever exhausted).
// R10: NON-TEMPORAL logit loads -> 27.75 us (L1/L2 allocation churn real).
// R11 FAILED: fused finish via same-address device atomics -> 8192 serialized
//     coherent-point RMWs -> 115 us. Both fusion mechanisms are dead ends;
//     the ~3 us second dispatch is the cheapest correct finish.

constexpr int BATCH = 4096;
constexpr int NPART = BATCH / 2;           // 2048 blocks, 2 rows each
constexpr float W_NEG_F = 1.0f / 4095.0f;  // matches fp32 W_NEG in reference

typedef float floatx4 __attribute__((ext_vector_type(4)));

__device__ __forceinline__ void pl_pair(float x, float y, bool lab,
                                        float& sum_all, float& sum_pos,
                                        int& pos, int& cor) {
    const float e = y - x;            // d when lab==0
    // log(1+exp(-|d|)) is label-independent since |d|=|e|
    const float t = __logf(1.f + __expf(-fabsf(e)));
    const float m = lab ? fmaxf(-e, 0.f) : fmaxf(e, 0.f);  // max(d,0)
    const float nll = m + t;
    sum_all += nll;
    sum_pos += lab ? nll : 0.f;
    pos += lab ? 1 : 0;
    cor += ((y > x) == lab) ? 1 : 0;  // argmax with first-index tie-break
}

__device__ __forceinline__ floatx4 ntload4(const float* p) {
    return __builtin_nontemporal_load(reinterpret_cast<const floatx4*>(p));
}

// ---------------- kernel 1: per-2-row partials (deterministic) --------------
__global__ __launch_bounds__(256) void pl_partials(
    const float* __restrict__ logits,   // [BATCH*BATCH*2]
    const int* __restrict__ tp,         // [BATCH]
    const int* __restrict__ tg,         // [BATCH]
    double* __restrict__ part_wnll,     // [NPART]
    int* __restrict__ part_pos,         // [NPART]
    int* __restrict__ part_cor)         // [NPART]
{
    const int t = threadIdx.x;
    const int row0 = 2 * blockIdx.x;
    const float* rowA = logits + (size_t)row0 * (2 * BATCH);
    const float* rowB = rowA + 2 * BATCH;
    const int2* tg2 = reinterpret_cast<const int2*>(tg);

    // All loads upfront, named registers, no barrier before compute.
    // Gallery int2s cached (reused by all blocks); logits NON-TEMPORAL
    // (read exactly once -> skip cache allocation).
    const int2 g0 = tg2[t];
    const int2 g1 = tg2[t + 256];
    const int2 g2 = tg2[t + 512];
    const int2 g3 = tg2[t + 768];
    const int2 g4 = tg2[t + 1024];
    const int2 g5 = tg2[t + 1280];
    const int2 g6 = tg2[t + 1536];
    const int2 g7 = tg2[t + 1792];
    const floatx4 a0 = ntload4(rowA + 4 * t);
    const floatx4 a1 = ntload4(rowA + 4 * (t + 256));
    const floatx4 a2 = ntload4(rowA + 4 * (t + 512));
    const floatx4 a3 = ntload4(rowA + 4 * (t + 768));
    const floatx4 a4 = ntload4(rowA + 4 * (t + 1024));
    const floatx4 a5 = ntload4(rowA + 4 * (t + 1280));
    const floatx4 a6 = ntload4(rowA + 4 * (t + 1536));
    const floatx4 a7 = ntload4(rowA + 4 * (t + 1792));
    const floatx4 b0 = ntload4(rowB + 4 * t);
    const floatx4 b1 = ntload4(rowB + 4 * (t + 256));
    const floatx4 b2 = ntload4(rowB + 4 * (t + 512));
    const floatx4 b3 = ntload4(rowB + 4 * (t + 768));
    const floatx4 b4 = ntload4(rowB + 4 * (t + 1024));
    const floatx4 b5 = ntload4(rowB + 4 * (t + 1280));
    const floatx4 b6 = ntload4(rowB + 4 * (t + 1536));
    const floatx4 b7 = ntload4(rowB + 4 * (t + 1792));
    const int my0 = tp[row0];      // wave-uniform -> scalar loads
    const int my1 = tp[row0 + 1];

    float sum_all = 0.f;   // nll over all pairs this thread sees (both rows)
    float sum_pos = 0.f;   // nll over positive pairs only
    int pos = 0, cor = 0;

#define PL_CHUNK(Q, G, MY)                                                   \
    pl_pair((Q).x, (Q).y, (MY) == (G).x, sum_all, sum_pos, pos, cor);        \
    pl_pair((Q).z, (Q).w, (MY) == (G).y, sum_all, sum_pos, pos, cor);
    PL_CHUNK(a0, g0, my0) PL_CHUNK(a1, g1, my0) PL_CHUNK(a2, g2, my0)
    PL_CHUNK(a3, g3, my0) PL_CHUNK(a4, g4, my0) PL_CHUNK(a5, g5, my0)
    PL_CHUNK(a6, g6, my0) PL_CHUNK(a7, g7, my0)
    PL_CHUNK(b0, g0, my1) PL_CHUNK(b1, g1, my1) PL_CHUNK(b2, g2, my1)
    PL_CHUNK(b3, g3, my1) PL_CHUNK(b4, g4, my1) PL_CHUNK(b5, g5, my1)
    PL_CHUNK(b6, g6, my1) PL_CHUNK(b7, g7, my1)
#undef PL_CHUNK

    // weighted combination, then wave64 shuffle reduce (double for the sum)
    double dw = (double)W_NEG_F * (double)sum_all +
                (1.0 - (double)W_NEG_F) * (double)sum_pos;
#pragma unroll
    for (int off = 32; off > 0; off >>= 1) {
        dw += __shfl_down(dw, off);
        pos += __shfl_down(pos, off);
        cor += __shfl_down(cor, off);
    }
    __shared__ double s_dw[4];
    __shared__ int s_pos[4], s_cor[4];
    const int wave = t >> 6, lane = t & 63;
    if (lane == 0) { s_dw[wave] = dw; s_pos[wave] = pos; s_cor[wave] = cor; }
    __syncthreads();  // tail only — all loads already consumed
    if (t == 0) {
        part_wnll[blockIdx.x] = s_dw[0] + s_dw[1] + s_dw[2] + s_dw[3];
        part_pos[blockIdx.x] = s_pos[0] + s_pos[1] + s_pos[2] + s_pos[3];
        part_cor[blockIdx.x] = s_cor[0] + s_cor[1] + s_cor[2] + s_cor[3];
    }
}

// ---------------- kernel 2: fixed-order final reduce ----------------
__global__ __launch_bounds__(256) void pl_final(
    const double* __restrict__ part_wnll,
    const int* __restrict__ part_pos,
    const int* __restrict__ part_cor,
    float* __restrict__ out)            // out[0]=loss, out[1]=prec
{
    const int t = threadIdx.x;
    double dw = 0.0;
    long long pos = 0, cor = 0;
#pragma unroll
    for (int v = t; v < NPART; v += 256) {
        dw += part_wnll[v];
        pos += (long long)part_pos[v];
        cor += (long long)part_cor[v];
    }
#pragma unroll
    for (int off = 32; off > 0; off >>= 1) {
        dw += __shfl_down(dw, off);
        pos += __shfl_down(pos, off);
        cor += __shfl_down(cor, off);
    }
    __shared__ double s_dw[4];
    __shared__ long long s_pos[4], s_cor[4];
    const int wave = t >> 6, lane = t & 63;
    if (lane == 0) { s_dw[wave] = dw; s_pos[wave] = pos; s_cor[wave] = cor; }
    __syncthreads();
    if (t == 0) {
        const double tot = s_dw[0] + s_dw[1] + s_dw[2] + s_dw[3];
        const long long P = s_pos[0] + s_pos[1] + s_pos[2] + s_pos[3];
        const long long C = s_cor[0] + s_cor[1] + s_cor[2] + s_cor[3];
        const double NP = (double)BATCH * (double)BATCH;
        // sum_w is exact given the positive count
        const double sum_w = (double)P + (NP - (double)P) * (double)W_NEG_F;
        out[0] = (float)(tot / sum_w);
        out[1] = (float)(100.0 * (double)C / NP);
    }
}

extern "C" void kernel_launch(void* const* d_in, const int* in_sizes, int n_in,
                              void* d_out, int out_size, void* d_ws, size_t ws_size,
                              hipStream_t stream) {
    const float* logits = (const float*)d_in[0];  // cls_encode [4096,4096,2] f32
    const int* tp = (const int*)d_in[1];          // tar_probe  [4096] i32
    const int* tg = (const int*)d_in[2];          // tar_gallery[4096] i32
    float* out = (float*)d_out;                   // [loss, prec]

    // workspace layout: 2048 doubles | 2048 ints | 2048 ints  (24 KiB)
    double* part_wnll = (double*)d_ws;
    int* part_pos = (int*)((char*)d_ws + NPART * sizeof(double));
    int* part_cor = part_pos + NPART;

    pl_partials<<<NPART, 256, 0, stream>>>(logits, tp, tg, part_wnll, part_pos,
                                           part_cor);
    pl_final<<<1, 256, 0, stream>>>(part_wnll, part_pos, part_cor, out);
}